// Round 7
// baseline (1328.312 us; speedup 1.0000x reference)
//
#include <hip/hip_runtime.h>
#include <hip/hip_bf16.h>
#include <math.h>

#define NQn 100000
#define NKVn 100000
#define NEn 2000000
// D=64, H=4, F=16

// ---------------- zero-init (acc + den) ------------------------------------
__global__ void zero_kernel(float4* __restrict__ p, int n4) {
    int i = blockIdx.x * blockDim.x + threadIdx.x;
    int stride = gridDim.x * blockDim.x;
    for (; i < n4; i += stride) p[i] = make_float4(0.f, 0.f, 0.f, 0.f);
}

// ---------------- q projection -> bf16 packed rows (32 uints = 64 bf16) ----
__global__ void qproj_kernel(const float* __restrict__ x, const float* __restrict__ W,
                             unsigned* __restrict__ qh) {
    __shared__ float Wl[64 * 64];
    for (int i = threadIdx.x; i < 64 * 64; i += blockDim.x) Wl[i] = W[i];
    __syncthreads();
    const int lane = threadIdx.x & 63;
    const int wid  = blockIdx.x * (blockDim.x >> 6) + (threadIdx.x >> 6);
    const int nw   = gridDim.x * (blockDim.x >> 6);
    for (int r = wid; r < NQn; r += nw) {
        float xv = x[(size_t)r * 64 + lane];
        float acc = 0.f;
        #pragma unroll
        for (int k = 0; k < 64; ++k)
            acc += __shfl(xv, k, 64) * Wl[k * 64 + lane];
        // pack pairs: lane j<32 writes uint of dims (2j, 2j+1)
        float a = __shfl(acc, 2 * (lane & 31), 64);
        float b = __shfl(acc, 2 * (lane & 31) + 1, 64);
        if (lane < 32) {
            unsigned ua = __bfloat16_as_ushort(__float2bfloat16(a));
            unsigned ub = __bfloat16_as_ushort(__float2bfloat16(b));
            qh[(size_t)r * 32 + lane] = ua | (ub << 16);
        }
    }
}

// ---------------- kv projection -> packed bf16 row [k(64) | v(64)] --------
__global__ void kvproj_kernel(const float* __restrict__ x, const float* __restrict__ W,
                              __hip_bfloat16* __restrict__ outh) {
    __shared__ float Wl[64 * 128];
    for (int i = threadIdx.x; i < 64 * 128; i += blockDim.x) Wl[i] = W[i];
    __syncthreads();
    const int lane = threadIdx.x & 63;
    const int wid  = blockIdx.x * (blockDim.x >> 6) + (threadIdx.x >> 6);
    const int nw   = gridDim.x * (blockDim.x >> 6);
    for (int r = wid; r < NKVn; r += nw) {
        float xv = x[(size_t)r * 64 + lane];
        float acc0 = 0.f, acc1 = 0.f;
        #pragma unroll
        for (int k = 0; k < 64; ++k) {
            float xk = __shfl(xv, k, 64);
            acc0 += xk * Wl[k * 128 + lane];        // k dim `lane`
            acc1 += xk * Wl[k * 128 + lane + 64];   // v dim `lane`
        }
        outh[(size_t)r * 128 + lane]      = __float2bfloat16(acc0);
        outh[(size_t)r * 128 + 64 + lane] = __float2bfloat16(acc1);
    }
}

// ---------------- edge pass: bf16 gathers + f32 atomic scatter -------------
// wave per edge. kvh row = 64 uints: u[0..31] = k pairs, u[32..63] = v pairs.
// qh row = 32 uints (q pairs). Lane l<32: score pair l (head = l>>3).
// Lane l>=32: v pair j=l-32, accumulates into acc[t][2j], acc[t][2j+1].
__global__ void edge_kernel(const int* __restrict__ t, const int* __restrict__ s,
                            const unsigned* __restrict__ qh,
                            const unsigned* __restrict__ kvh,
                            float* __restrict__ acc, float* __restrict__ den) {
    const int lane = threadIdx.x & 63;
    const int wid  = blockIdx.x * (blockDim.x >> 6) + (threadIdx.x >> 6);
    const int nw   = gridDim.x * (blockDim.x >> 6);
    for (int e = wid; e < NEn; e += nw) {
        int ti = t[e], si = s[e];
        unsigned u  = kvh[(size_t)si * 64 + lane];
        unsigned qu = qh[(size_t)ti * 32 + (lane & 31)];
        float ea = __uint_as_float(u << 16);            // element 2j
        float eb = __uint_as_float(u & 0xffff0000u);    // element 2j+1
        float qa = __uint_as_float(qu << 16);
        float qb = __uint_as_float(qu & 0xffff0000u);
        float p = qa * ea + qb * eb;                    // valid lanes 0-31
        p += __shfl_xor(p, 4, 64);
        p += __shfl_xor(p, 2, 64);
        p += __shfl_xor(p, 1, 64);
        float ex = __expf(p * 0.25f);                   // /sqrt(F), F=16
        float exv = __shfl(ex, lane & 31, 64);          // v-lane gets head's ex
        if (lane >= 32) {
            int j = lane - 32;
            atomicAdd(&acc[(size_t)ti * 64 + 2 * j],     exv * ea);
            atomicAdd(&acc[(size_t)ti * 64 + 2 * j + 1], exv * eb);
        } else if ((lane & 7) == 0) {
            atomicAdd(&den[(size_t)ti * 4 + (lane >> 3)], ex);
        }
    }
}

// ---------------- epilogue: normalize + @ Wo + bo --------------------------
__global__ void out_kernel(const float* __restrict__ acc, const float* __restrict__ den,
                           const float* __restrict__ Wo, const float* __restrict__ bo,
                           float* __restrict__ out) {
    __shared__ float Wl[64 * 64];
    for (int i = threadIdx.x; i < 64 * 64; i += blockDim.x) Wl[i] = Wo[i];
    __syncthreads();
    const int lane = threadIdx.x & 63;
    const int wid  = blockIdx.x * (blockDim.x >> 6) + (threadIdx.x >> 6);
    const int nw   = gridDim.x * (blockDim.x >> 6);
    const float b = bo[lane];
    for (int r = wid; r < NQn; r += nw) {
        float a  = acc[(size_t)r * 64 + lane];
        float d  = den[(size_t)r * 4 + (lane >> 4)];    // head = lane>>4
        float val = (d > 0.f) ? a / d : 0.f;            // empty segment -> 0
        float o = b;
        #pragma unroll
        for (int k = 0; k < 64; ++k)
            o += __shfl(val, k, 64) * Wl[k * 64 + lane];
        out[(size_t)r * 64 + lane] = o;
    }
}

extern "C" void kernel_launch(void* const* d_in, const int* in_sizes, int n_in,
                              void* d_out, int out_size, void* d_ws, size_t ws_size,
                              hipStream_t stream) {
    const float* input = (const float*)d_in[0];
    const float* other = (const float*)d_in[1];
    const int*   t     = (const int*)  d_in[2];
    const int*   s     = (const int*)  d_in[3];
    const float* Wq    = (const float*)d_in[4];
    const float* Wkv   = (const float*)d_in[5];
    const float* Wo    = (const float*)d_in[6];
    const float* bo    = (const float*)d_in[7];
    float* out = (float*)d_out;

    // workspace layout
    char* w = (char*)d_ws;
    unsigned*       qh  = (unsigned*)w;          w += (size_t)NQn * 32 * 4;    // 12.8 MB
    __hip_bfloat16* kvh = (__hip_bfloat16*)w;    w += (size_t)NKVn * 128 * 2;  // 25.6 MB
    float* acc = (float*)w;                      w += (size_t)NQn * 64 * 4;    // 25.6 MB
    float* den = (float*)w;                      w += (size_t)NQn * 4 * 4;     // 1.6 MB

    // zero the atomic accumulators (acc + den contiguous)
    int n4 = (NQn * 64 + NQn * 4) / 4;
    zero_kernel <<<2048, 256, 0, stream>>>((float4*)acc, n4);

    qproj_kernel <<<1024, 256, 0, stream>>>(input, Wq, qh);
    kvproj_kernel<<<1024, 256, 0, stream>>>(other, Wkv, (__hip_bfloat16*)kvh);
    edge_kernel  <<<4096, 256, 0, stream>>>(t, s, qh, (const unsigned*)kvh, acc, den);
    out_kernel   <<<1024, 256, 0, stream>>>(acc, den, Wo, bo, out);
}

// Round 8
// 916.579 us; speedup vs baseline: 1.4492x; 1.4492x over previous
//
#include <hip/hip_runtime.h>
#include <hip/hip_bf16.h>
#include <math.h>

#define NQn 100000
#define NKVn 100000
#define NEn 2000000
// D=64, H=4, F=16

// ---------------- zero-init (acc + den) ------------------------------------
__global__ void zero_kernel(float4* __restrict__ p, int n4) {
    int i = blockIdx.x * blockDim.x + threadIdx.x;
    int stride = gridDim.x * blockDim.x;
    for (; i < n4; i += stride) p[i] = make_float4(0.f, 0.f, 0.f, 0.f);
}

// ---------------- q projection -> bf16 packed rows (32 uints = 64 bf16) ----
__global__ void qproj_kernel(const float* __restrict__ x, const float* __restrict__ W,
                             unsigned* __restrict__ qh) {
    __shared__ float Wl[64 * 64];
    for (int i = threadIdx.x; i < 64 * 64; i += blockDim.x) Wl[i] = W[i];
    __syncthreads();
    const int lane = threadIdx.x & 63;
    const int wid  = blockIdx.x * (blockDim.x >> 6) + (threadIdx.x >> 6);
    const int nw   = gridDim.x * (blockDim.x >> 6);
    for (int r = wid; r < NQn; r += nw) {
        float xv = x[(size_t)r * 64 + lane];
        float acc = 0.f;
        #pragma unroll
        for (int k = 0; k < 64; ++k)
            acc += __shfl(xv, k, 64) * Wl[k * 64 + lane];
        // pack pairs: lane j<32 writes uint of dims (2j, 2j+1)
        float a = __shfl(acc, 2 * (lane & 31), 64);
        float b = __shfl(acc, 2 * (lane & 31) + 1, 64);
        if (lane < 32) {
            unsigned ua = __bfloat16_as_ushort(__float2bfloat16(a));
            unsigned ub = __bfloat16_as_ushort(__float2bfloat16(b));
            qh[(size_t)r * 32 + lane] = ua | (ub << 16);
        }
    }
}

// ---------------- kv projection -> packed bf16 row [k(64) | v(64)] --------
__global__ void kvproj_kernel(const float* __restrict__ x, const float* __restrict__ W,
                              __hip_bfloat16* __restrict__ outh) {
    __shared__ float Wl[64 * 128];
    for (int i = threadIdx.x; i < 64 * 128; i += blockDim.x) Wl[i] = W[i];
    __syncthreads();
    const int lane = threadIdx.x & 63;
    const int wid  = blockIdx.x * (blockDim.x >> 6) + (threadIdx.x >> 6);
    const int nw   = gridDim.x * (blockDim.x >> 6);
    for (int r = wid; r < NKVn; r += nw) {
        float xv = x[(size_t)r * 64 + lane];
        float acc0 = 0.f, acc1 = 0.f;
        #pragma unroll
        for (int k = 0; k < 64; ++k) {
            float xk = __shfl(xv, k, 64);
            acc0 += xk * Wl[k * 128 + lane];        // k dim `lane`
            acc1 += xk * Wl[k * 128 + lane + 64];   // v dim `lane`
        }
        outh[(size_t)r * 128 + lane]      = __float2bfloat16(acc0);
        outh[(size_t)r * 128 + 64 + lane] = __float2bfloat16(acc1);
    }
}

// ---------------- edge pass: bf16 gathers + ONE contiguous f32 atomic ------
// wave per edge. kvh row = 64 uints: u[0..31] = k pairs, u[32..63] = v pairs.
// qh row = 32 uints (q pairs). Lanes 0-31 compute score pair `lane`
// (head = lane>>3). Then every lane l accumulates acc[ti*64 + l] with a
// single 64-lane atomic instruction over the contiguous 256B row.
__global__ void edge_kernel(const int* __restrict__ t, const int* __restrict__ s,
                            const unsigned* __restrict__ qh,
                            const unsigned* __restrict__ kvh,
                            float* __restrict__ acc, float* __restrict__ den) {
    const int lane = threadIdx.x & 63;
    const int wid  = blockIdx.x * (blockDim.x >> 6) + (threadIdx.x >> 6);
    const int nw   = gridDim.x * (blockDim.x >> 6);
    for (int e = wid; e < NEn; e += nw) {
        int ti = t[e], si = s[e];
        unsigned u  = kvh[(size_t)si * 64 + lane];
        unsigned qu = qh[(size_t)ti * 32 + (lane & 31)];
        float ea = __uint_as_float(u << 16);            // pair elem 2j
        float eb = __uint_as_float(u & 0xffff0000u);    // pair elem 2j+1
        float qa = __uint_as_float(qu << 16);
        float qb = __uint_as_float(qu & 0xffff0000u);
        float p = qa * ea + qb * eb;                    // valid in lanes 0-31
        p += __shfl_xor(p, 4, 64);
        p += __shfl_xor(p, 2, 64);
        p += __shfl_xor(p, 1, 64);
        float ex = __expf(p * 0.25f);                   // /sqrt(F), F=16
        // per-head ex to all lanes: head of dim `lane` is lane>>4,
        // its reduce result lives in k-lane (lane>>4)*8
        float exv = __shfl(ex, (lane >> 4) << 3, 64);
        // v element `lane`: packed uint held by lane 32+(lane>>1)
        unsigned uv = __shfl(u, 32 + (lane >> 1), 64);
        float vv = __uint_as_float((lane & 1) ? (uv & 0xffff0000u) : (uv << 16));
        atomicAdd(&acc[(size_t)ti * 64 + lane], exv * vv);   // one 256B row
        if ((lane & 15) == 0)
            atomicAdd(&den[(size_t)ti * 4 + (lane >> 4)], exv);
    }
}

// ---------------- epilogue: normalize + @ Wo + bo --------------------------
__global__ void out_kernel(const float* __restrict__ acc, const float* __restrict__ den,
                           const float* __restrict__ Wo, const float* __restrict__ bo,
                           float* __restrict__ out) {
    __shared__ float Wl[64 * 64];
    for (int i = threadIdx.x; i < 64 * 64; i += blockDim.x) Wl[i] = Wo[i];
    __syncthreads();
    const int lane = threadIdx.x & 63;
    const int wid  = blockIdx.x * (blockDim.x >> 6) + (threadIdx.x >> 6);
    const int nw   = gridDim.x * (blockDim.x >> 6);
    const float b = bo[lane];
    for (int r = wid; r < NQn; r += nw) {
        float a  = acc[(size_t)r * 64 + lane];
        float d  = den[(size_t)r * 4 + (lane >> 4)];    // head = lane>>4
        float val = (d > 0.f) ? a / d : 0.f;            // empty segment -> 0
        float o = b;
        #pragma unroll
        for (int k = 0; k < 64; ++k)
            o += __shfl(val, k, 64) * Wl[k * 64 + lane];
        out[(size_t)r * 64 + lane] = o;
    }
}

extern "C" void kernel_launch(void* const* d_in, const int* in_sizes, int n_in,
                              void* d_out, int out_size, void* d_ws, size_t ws_size,
                              hipStream_t stream) {
    const float* input = (const float*)d_in[0];
    const float* other = (const float*)d_in[1];
    const int*   t     = (const int*)  d_in[2];
    const int*   s     = (const int*)  d_in[3];
    const float* Wq    = (const float*)d_in[4];
    const float* Wkv   = (const float*)d_in[5];
    const float* Wo    = (const float*)d_in[6];
    const float* bo    = (const float*)d_in[7];
    float* out = (float*)d_out;

    // workspace layout
    char* w = (char*)d_ws;
    unsigned*       qh  = (unsigned*)w;          w += (size_t)NQn * 32 * 4;    // 12.8 MB
    __hip_bfloat16* kvh = (__hip_bfloat16*)w;    w += (size_t)NKVn * 128 * 2;  // 25.6 MB
    float* acc = (float*)w;                      w += (size_t)NQn * 64 * 4;    // 25.6 MB
    float* den = (float*)w;                      w += (size_t)NQn * 4 * 4;     // 1.6 MB

    // zero the atomic accumulators (acc + den contiguous)
    int n4 = (NQn * 64 + NQn * 4) / 4;
    zero_kernel <<<2048, 256, 0, stream>>>((float4*)acc, n4);

    qproj_kernel <<<2048, 256, 0, stream>>>(input, Wq, qh);
    kvproj_kernel<<<2048, 256, 0, stream>>>(other, Wkv, (__hip_bfloat16*)kvh);
    edge_kernel  <<<4096, 256, 0, stream>>>(t, s, qh, (const unsigned*)kvh, acc, den);
    out_kernel   <<<2048, 256, 0, stream>>>(acc, den, Wo, bo, out);
}